// Round 1
// baseline (2013.528 us; speedup 1.0000x reference)
//
#include <hip/hip_runtime.h>
#include <stdint.h>

#define Bd   128
#define Td   1000
#define INd  700
#define Hd   512
#define OUTd 20

// ---------------------------------------------------------------------------
// GEMM1: proj[m][n] = sum_k X[m][k] * W1[n][k] + b1[n]
// X: [128000, 700] row-major, W1: [512, 700] row-major (both K-contiguous)
// Block tile 128x128, BK=8, 256 threads, 8x8 micro-tile per thread.
// ---------------------------------------------------------------------------
__global__ __launch_bounds__(256) void gemm1_kernel(
    const float* __restrict__ X, const float* __restrict__ W1,
    const float* __restrict__ b1, float* __restrict__ proj) {
  __shared__ __align__(16) float As[8][128];
  __shared__ __align__(16) float Bs[8][128];
  const int m0 = blockIdx.x * 128;
  const int n0 = blockIdx.y * 128;
  const int tid = threadIdx.x;
  const int tx = tid & 15, ty = tid >> 4;
  const int lrow = tid >> 1;          // 0..127
  const int lcol = (tid & 1) << 2;    // 0 or 4

  const float* Xp = X + (size_t)(m0 + lrow) * INd + lcol;
  const float* Wp = W1 + (size_t)(n0 + lrow) * INd + lcol;

  float acc[8][8];
#pragma unroll
  for (int i = 0; i < 8; ++i)
#pragma unroll
    for (int j = 0; j < 8; ++j) acc[i][j] = 0.f;

  for (int k0 = 0; k0 < INd; k0 += 8) {
    float4 av = make_float4(0.f, 0.f, 0.f, 0.f);
    float4 bv = make_float4(0.f, 0.f, 0.f, 0.f);
    if (k0 + lcol + 4 <= INd) {            // 700 % 4 == 0, rows 16B-aligned
      av = *(const float4*)(Xp + k0);
      bv = *(const float4*)(Wp + k0);
    }
    __syncthreads();
    As[lcol + 0][lrow] = av.x; As[lcol + 1][lrow] = av.y;
    As[lcol + 2][lrow] = av.z; As[lcol + 3][lrow] = av.w;
    Bs[lcol + 0][lrow] = bv.x; Bs[lcol + 1][lrow] = bv.y;
    Bs[lcol + 2][lrow] = bv.z; Bs[lcol + 3][lrow] = bv.w;
    __syncthreads();
#pragma unroll
    for (int k = 0; k < 8; ++k) {
      float a[8], b[8];
      *(float4*)&a[0] = *(const float4*)&As[k][ty * 8];
      *(float4*)&a[4] = *(const float4*)&As[k][ty * 8 + 4];
      *(float4*)&b[0] = *(const float4*)&Bs[k][tx * 8];
      *(float4*)&b[4] = *(const float4*)&Bs[k][tx * 8 + 4];
#pragma unroll
      for (int i = 0; i < 8; ++i)
#pragma unroll
        for (int j = 0; j < 8; ++j) acc[i][j] = fmaf(a[i], b[j], acc[i][j]);
    }
  }

#pragma unroll
  for (int i = 0; i < 8; ++i) {
    const int m = m0 + ty * 8 + i;
    float* Cp = proj + (size_t)m * Hd + n0 + tx * 8;
#pragma unroll
    for (int j = 0; j < 8; ++j) Cp[j] = acc[i][j] + b1[n0 + tx * 8 + j];
  }
}

// ---------------------------------------------------------------------------
// Scan1: per-(b,h) LIF + dendritic filter over t; emit spike bitmasks.
// spk[(b*Td + t)*8 + h/64] = 64-bit mask of fires for h-chunk.
// ---------------------------------------------------------------------------
__global__ __launch_bounds__(256) void scan1_kernel(
    const float* __restrict__ proj, const float* __restrict__ tau_m1,
    const float* __restrict__ tau_n1, const float* __restrict__ mem1_0,
    unsigned long long* __restrict__ spk) {
  const int gid = blockIdx.x * 256 + threadIdx.x;   // 0..65535
  const int b = gid >> 9;
  const int h = gid & 511;
  const float am = 1.f / (1.f + expf(-tau_m1[h]));
  const float bn = 1.f / (1.f + expf(-tau_n1[h]));
  const float omam = 1.f - am, ombn = 1.f - bn;
  float mem = mem1_0[(b << 9) | h];
  float d = 0.f, s = 0.f;
  const float* pp = proj + (size_t)b * Td * Hd + h;
  unsigned long long* sp = spk + (size_t)b * Td * 8 + (h >> 6);
  const int lane = threadIdx.x & 63;
  for (int t = 0; t < Td; ++t) {
    const float p = pp[(size_t)t * Hd];
    d = bn * d + ombn * p;
    mem = am * mem + omam * d - s;      // VTH=1, soft reset with previous spike
    const bool fire = mem > 1.0f;       // spike_fn(mem - VTH): (mem-VTH) > 0
    s = fire ? 1.f : 0.f;
    const unsigned long long mask = __ballot(fire);
    if (lane == 0) sp[(size_t)t * 8] = mask;
  }
}

// ---------------------------------------------------------------------------
// GEMM2: R[m][o] = b2[o] + sum over set bits h of W2[o][h].
// Wave: lanes 0..59 = 3 m-groups x 20 outputs; 8 m-iters -> 96 m per block.
// W2 staged in LDS as [h][o] (40 KB).
// ---------------------------------------------------------------------------
__global__ __launch_bounds__(256) void gemm2_kernel(
    const unsigned long long* __restrict__ spk, const float* __restrict__ W2,
    const float* __restrict__ b2, float* __restrict__ R, int Mtotal) {
  __shared__ float W2s[Hd * OUTd];
  const int tid = threadIdx.x;
  for (int idx = tid; idx < Hd * OUTd; idx += 256) {
    const int h = idx / OUTd, o = idx - h * OUTd;
    W2s[idx] = W2[o * Hd + h];
  }
  __syncthreads();
  const int wave = tid >> 6, lane = tid & 63;
  const int mg = lane / OUTd;            // 0..3 (3 = idle lane)
  const int o = lane - mg * OUTd;        // 0..19
  if (mg >= 3) return;                   // no barriers after this point
  const float bias = b2[o];
  const int mbase = blockIdx.x * 96 + wave * 24 + mg;
#pragma unroll 1
  for (int i = 0; i < 8; ++i) {
    const int m = mbase + i * 3;
    if (m >= Mtotal) break;
    float r = bias;
    const unsigned long long* mp = spk + (size_t)m * 8;
#pragma unroll
    for (int c = 0; c < 8; ++c) {
      unsigned long long mask = mp[c];
      const float* wrow = W2s + (c << 6) * OUTd + o;
      while (mask) {
        const int j = __builtin_ctzll(mask);
        mask &= mask - 1;
        r += wrow[j * OUTd];
      }
    }
    R[(size_t)m * OUTd + o] = r;
  }
}

// ---------------------------------------------------------------------------
// Scan2: per-(b,o) leaky readout; writes out[b][t][o] = mem2.
// ---------------------------------------------------------------------------
__global__ __launch_bounds__(256) void scan2_kernel(
    const float* __restrict__ R, const float* __restrict__ tau_m2,
    const float* __restrict__ mem2_0, float* __restrict__ out) {
  const int gid = blockIdx.x * 256 + threadIdx.x;
  if (gid >= Bd * OUTd) return;
  const int b = gid / OUTd, o = gid - b * OUTd;
  const float a2 = 1.f / (1.f + expf(-tau_m2[o]));
  const float oma2 = 1.f - a2;
  float mem = mem2_0[gid];
  const float* Rp = R + (size_t)b * Td * OUTd + o;
  float* Op = out + (size_t)b * Td * OUTd + o;
  for (int t = 0; t < Td; ++t) {
    mem = a2 * mem + oma2 * Rp[(size_t)t * OUTd];
    Op[(size_t)t * OUTd] = mem;
  }
}

extern "C" void kernel_launch(void* const* d_in, const int* in_sizes, int n_in,
                              void* d_out, int out_size, void* d_ws, size_t ws_size,
                              hipStream_t stream) {
  const float* x      = (const float*)d_in[0];
  const float* W1     = (const float*)d_in[1];
  const float* b1     = (const float*)d_in[2];
  const float* tau_m1 = (const float*)d_in[3];
  const float* tau_n1 = (const float*)d_in[4];
  const float* W2     = (const float*)d_in[5];
  const float* b2     = (const float*)d_in[6];
  const float* tau_m2 = (const float*)d_in[7];
  const float* mem1_0 = (const float*)d_in[8];
  const float* mem2_0 = (const float*)d_in[9];
  float* out = (float*)d_out;

  const int M = Bd * Td;  // 128000
  // Workspace layout: proj (262.1 MB) | spike masks (8.2 MB) | R (10.2 MB)
  float* proj = (float*)d_ws;
  unsigned long long* spk =
      (unsigned long long*)((char*)d_ws + (size_t)M * Hd * sizeof(float));
  float* R = (float*)((char*)spk + (size_t)M * 8 * sizeof(unsigned long long));

  gemm1_kernel<<<dim3(M / 128, Hd / 128), 256, 0, stream>>>(x, W1, b1, proj);
  scan1_kernel<<<dim3(Bd * Hd / 256), 256, 0, stream>>>(proj, tau_m1, tau_n1,
                                                        mem1_0, spk);
  gemm2_kernel<<<dim3((M + 95) / 96), 256, 0, stream>>>(spk, W2, b2, R, M);
  scan2_kernel<<<dim3((Bd * OUTd + 255) / 256), 256, 0, stream>>>(R, tau_m2,
                                                                  mem2_0, out);
}